// Round 1
// baseline (19082.390 us; speedup 1.0000x reference)
//
#include <hip/hip_runtime.h>

#define NROWS 50000
#define DIM   256
#define SHOPS 6
#define ROUNDS 4
#define EPSV  1e-5f

#define BM 128
#define BN 128
#define BK 16
#define LDA (BM + 4)   // padded LDS stride (floats); 132*4=528B, 16B-aligned
#define LDB (BN + 4)

// C[sc[j], n] (+)= sum_k A[g[j], k] * W[n, k]
// MODE 0: identity gather/scatter, plain float4 store (temp init / ctr2 GEMM)
// MODE 1: gathered rows, atomicAdd scatter, 12 segments via blockIdx.z
template<int MODE>
__global__ __launch_bounds__(256)
void gemm_gs(const float* __restrict__ A,
             const float* __restrict__ Wpre, const float* __restrict__ Wsuc,
             const int* __restrict__ nhp, const int* __restrict__ nhs,
             const int* __restrict__ pidx, const int* __restrict__ sidx,
             float* __restrict__ C, int round)
{
    __shared__ float As[BK][LDA];
    __shared__ float Ws[BK][LDB];

    const int tid = threadIdx.x;
    const int tx = tid & 15;        // 0..15 -> output cols tx*8..tx*8+7
    const int ty = tid >> 4;        // 0..15 -> output rows ty*8..ty*8+7
    const int bm0 = blockIdx.x * BM;
    const int bn0 = blockIdx.y * BN;

    const float* W;
    const int* g = nullptr;
    const int* sc = nullptr;
    if (MODE == 0) {
        W = Wpre + (size_t)round * DIM * DIM;
    } else {
        const int seg = blockIdx.z;       // 0..11
        const int k   = seg >> 1;
        const int dir = seg & 1;          // 0: pre-branch, 1: suc-branch
        W  = (dir ? Wsuc : Wpre) + ((size_t)(round * SHOPS + k)) * DIM * DIM;
        g  = (dir ? nhs  : nhp)  + k * NROWS;
        sc = (dir ? pidx : sidx) + k * NROWS;
    }

    float acc[8][8];
    #pragma unroll
    for (int i = 0; i < 8; ++i)
        #pragma unroll
        for (int j = 0; j < 8; ++j) acc[i][j] = 0.0f;

    for (int kt = 0; kt < DIM; kt += BK) {
        // Load A tile (BM x BK) and W tile (BN x BK), transposed into LDS.
        // 128 rows * 16 k = 512 float4 per tile; 2 per thread.
        #pragma unroll
        for (int it = 0; it < 2; ++it) {
            const int f   = tid + it * 256;   // 0..511
            const int row = f >> 2;           // 0..127
            const int c4  = (f & 3) * 4;      // 0,4,8,12

            const int ar = bm0 + row;
            float4 av = make_float4(0.f, 0.f, 0.f, 0.f);
            if (ar < NROWS) {
                const int grow = (MODE == 1) ? g[ar] : ar;
                av = *(const float4*)(A + (size_t)grow * DIM + kt + c4);
            }
            As[c4 + 0][row] = av.x;
            As[c4 + 1][row] = av.y;
            As[c4 + 2][row] = av.z;
            As[c4 + 3][row] = av.w;

            const int wr = bn0 + row;         // < 256 always
            const float4 wv = *(const float4*)(W + (size_t)wr * DIM + kt + c4);
            Ws[c4 + 0][row] = wv.x;
            Ws[c4 + 1][row] = wv.y;
            Ws[c4 + 2][row] = wv.z;
            Ws[c4 + 3][row] = wv.w;
        }
        __syncthreads();

        #pragma unroll
        for (int kk = 0; kk < BK; ++kk) {
            const float4 a0 = *(const float4*)&As[kk][ty * 8];
            const float4 a1 = *(const float4*)&As[kk][ty * 8 + 4];
            const float4 b0 = *(const float4*)&Ws[kk][tx * 8];
            const float4 b1 = *(const float4*)&Ws[kk][tx * 8 + 4];
            const float a[8] = {a0.x, a0.y, a0.z, a0.w, a1.x, a1.y, a1.z, a1.w};
            const float b[8] = {b0.x, b0.y, b0.z, b0.w, b1.x, b1.y, b1.z, b1.w};
            #pragma unroll
            for (int i = 0; i < 8; ++i)
                #pragma unroll
                for (int j = 0; j < 8; ++j)
                    acc[i][j] += a[i] * b[j];
        }
        __syncthreads();
    }

    // Epilogue
    #pragma unroll
    for (int i = 0; i < 8; ++i) {
        const int r = bm0 + ty * 8 + i;
        if (r >= NROWS) continue;
        if (MODE == 1) {
            const int orow = sc[r];
            float* crow = C + (size_t)orow * DIM + bn0 + tx * 8;
            #pragma unroll
            for (int j = 0; j < 8; ++j) atomicAdd(crow + j, acc[i][j]);
        } else {
            float* crow = C + (size_t)r * DIM + bn0 + tx * 8;
            *(float4*)(crow)     = make_float4(acc[i][0], acc[i][1], acc[i][2], acc[i][3]);
            *(float4*)(crow + 4) = make_float4(acc[i][4], acc[i][5], acc[i][6], acc[i][7]);
        }
    }
}

// GroupNorm(1 group) over a 256-wide row; one wave per row, 4 rows per block.
// MODE 0: out = relu(gn(in)*w+b)
// MODE 1: out = relu(gn(in)*w+b + res)
template<int MODE>
__global__ __launch_bounds__(256)
void gn_kernel(const float* __restrict__ in, const float* __restrict__ w,
               const float* __restrict__ b, const float* __restrict__ res,
               float* __restrict__ out)
{
    const int lane = threadIdx.x & 63;
    const int wv   = threadIdx.x >> 6;
    const int row  = blockIdx.x * 4 + wv;
    if (row >= NROWS) return;

    const float4 v = *(const float4*)(in + (size_t)row * DIM + lane * 4);
    float s  = v.x + v.y + v.z + v.w;
    float ss = v.x * v.x + v.y * v.y + v.z * v.z + v.w * v.w;
    #pragma unroll
    for (int off = 32; off >= 1; off >>= 1) {
        s  += __shfl_xor(s, off);
        ss += __shfl_xor(ss, off);
    }
    const float m   = s * (1.0f / DIM);
    const float var = ss * (1.0f / DIM) - m * m;
    const float inv = rsqrtf(var + EPSV);

    const float4 wv4 = *(const float4*)(w + lane * 4);
    const float4 bv4 = *(const float4*)(b + lane * 4);
    float4 o;
    o.x = (v.x - m) * inv * wv4.x + bv4.x;
    o.y = (v.y - m) * inv * wv4.y + bv4.y;
    o.z = (v.z - m) * inv * wv4.z + bv4.z;
    o.w = (v.w - m) * inv * wv4.w + bv4.w;

    if (MODE == 0) {
        o.x = fmaxf(o.x, 0.f);
        o.y = fmaxf(o.y, 0.f);
        o.z = fmaxf(o.z, 0.f);
        o.w = fmaxf(o.w, 0.f);
    } else {
        const float4 r4 = *(const float4*)(res + (size_t)row * DIM + lane * 4);
        o.x = fmaxf(o.x + r4.x, 0.f);
        o.y = fmaxf(o.y + r4.y, 0.f);
        o.z = fmaxf(o.z + r4.z, 0.f);
        o.w = fmaxf(o.w + r4.w, 0.f);
    }
    *(float4*)(out + (size_t)row * DIM + lane * 4) = o;
}

extern "C" void kernel_launch(void* const* d_in, const int* in_sizes, int n_in,
                              void* d_out, int out_size, void* d_ws, size_t ws_size,
                              hipStream_t stream)
{
    const float* lane   = (const float*)d_in[0];
    const float* W_ctr  = (const float*)d_in[1];
    const float* norm_w = (const float*)d_in[2];
    const float* norm_b = (const float*)d_in[3];
    const float* W_ctr2 = (const float*)d_in[4];
    const float* c2w    = (const float*)d_in[5];
    const float* c2b    = (const float*)d_in[6];
    const float* W_pre  = (const float*)d_in[7];
    const float* W_suc  = (const float*)d_in[8];
    const int*   pidx   = (const int*)d_in[9];
    const int*   sidx   = (const int*)d_in[10];
    const int*   nhp    = (const int*)d_in[11];
    const int*   nhs    = (const int*)d_in[12];

    float* X    = (float*)d_out;                        // current x / residual
    float* TEMP = (float*)d_ws;                         // accumulated messages, then h (in-place gn)
    float* Y    = TEMP + (size_t)NROWS * DIM;           // ctr2 GEMM output

    hipMemcpyAsync(X, lane, (size_t)NROWS * DIM * sizeof(float),
                   hipMemcpyDeviceToDevice, stream);

    const dim3 blk(256);
    const dim3 gg((NROWS + BM - 1) / BM, DIM / BN, 1);    // 391 x 2
    const dim3 gb((NROWS + BM - 1) / BM, DIM / BN, 12);   // 391 x 2 x 12
    const int  gnBlocks = (NROWS + 3) / 4;                // 12500

    for (int i = 0; i < ROUNDS; ++i) {
        // temp = x @ W_ctr[i].T   (plain store initializes TEMP)
        gemm_gs<0><<<gg, blk, 0, stream>>>(X, W_ctr, nullptr, nullptr, nullptr,
                                           nullptr, nullptr, TEMP, i);
        // 12 gather->GEMM->scatter-add branches
        gemm_gs<1><<<gb, blk, 0, stream>>>(X, W_pre, W_suc, nhp, nhs, pidx, sidx,
                                           TEMP, i);
        // h = relu(gn(temp)) in place
        gn_kernel<0><<<gnBlocks, blk, 0, stream>>>(TEMP, norm_w + i * DIM,
                                                   norm_b + i * DIM, nullptr, TEMP);
        // y = h @ W_ctr2[i].T
        gemm_gs<0><<<gg, blk, 0, stream>>>(TEMP, W_ctr2, nullptr, nullptr, nullptr,
                                           nullptr, nullptr, Y, i);
        // x = relu(gn(y) + x)
        gn_kernel<1><<<gnBlocks, blk, 0, stream>>>(Y, c2w + i * DIM,
                                                   c2b + i * DIM, X, X);
    }
}

// Round 2
// 8185.194 us; speedup vs baseline: 2.3313x; 2.3313x over previous
//
#include <hip/hip_runtime.h>

#define NROWS 50000
#define DIM   256
#define SHOPS 6
#define ROUNDS 4
#define EPSV  1e-5f

#define BM 128
#define BN 128
#define BK 16
#define LDA (BM + 4)
#define LDB (BN + 4)
#define ND ((size_t)NROWS * DIM)

// ---------------- plain GEMM: C = A @ W^T ----------------
// KIND 0: W and C passed directly (ctr / ctr2)
// KIND 1: batched message GEMMs; seg s = c0 + blockIdx.z selects W; C = YBUF slot z
template<int KIND>
__global__ __launch_bounds__(256)
void gemm_k(const float* __restrict__ A, const float* __restrict__ Wp,
            const float* __restrict__ Wpre, const float* __restrict__ Wsuc,
            float* __restrict__ Cp, float* __restrict__ YBUF,
            int round, int c0)
{
    __shared__ float As[BK][LDA];
    __shared__ float Ws[BK][LDB];

    const int tid = threadIdx.x;
    const int tx = tid & 15;
    const int ty = tid >> 4;
    const int bm0 = blockIdx.x * BM;
    const int bn0 = blockIdx.y * BN;

    const float* W;
    float* C;
    if (KIND == 0) {
        W = Wp; C = Cp;
    } else {
        const int s = c0 + blockIdx.z;
        const int k = s >> 1, dir = s & 1;
        W = (dir ? Wsuc : Wpre) + ((size_t)(round * SHOPS + k)) * DIM * DIM;
        C = YBUF + (size_t)blockIdx.z * ND;
    }

    float acc[8][8];
    #pragma unroll
    for (int i = 0; i < 8; ++i)
        #pragma unroll
        for (int j = 0; j < 8; ++j) acc[i][j] = 0.0f;

    for (int kt = 0; kt < DIM; kt += BK) {
        #pragma unroll
        for (int it = 0; it < 2; ++it) {
            const int f   = tid + it * 256;
            const int row = f >> 2;
            const int c4  = (f & 3) * 4;

            const int ar = bm0 + row;
            float4 av = make_float4(0.f, 0.f, 0.f, 0.f);
            if (ar < NROWS)
                av = *(const float4*)(A + (size_t)ar * DIM + kt + c4);
            As[c4 + 0][row] = av.x;
            As[c4 + 1][row] = av.y;
            As[c4 + 2][row] = av.z;
            As[c4 + 3][row] = av.w;

            const int wr = bn0 + row;
            const float4 wv = *(const float4*)(W + (size_t)wr * DIM + kt + c4);
            Ws[c4 + 0][row] = wv.x;
            Ws[c4 + 1][row] = wv.y;
            Ws[c4 + 2][row] = wv.z;
            Ws[c4 + 3][row] = wv.w;
        }
        __syncthreads();

        #pragma unroll
        for (int kk = 0; kk < BK; ++kk) {
            const float4 a0 = *(const float4*)&As[kk][ty * 8];
            const float4 a1 = *(const float4*)&As[kk][ty * 8 + 4];
            const float4 b0 = *(const float4*)&Ws[kk][tx * 8];
            const float4 b1 = *(const float4*)&Ws[kk][tx * 8 + 4];
            const float a[8] = {a0.x, a0.y, a0.z, a0.w, a1.x, a1.y, a1.z, a1.w};
            const float b[8] = {b0.x, b0.y, b0.z, b0.w, b1.x, b1.y, b1.z, b1.w};
            #pragma unroll
            for (int i = 0; i < 8; ++i)
                #pragma unroll
                for (int j = 0; j < 8; ++j)
                    acc[i][j] += a[i] * b[j];
        }
        __syncthreads();
    }

    #pragma unroll
    for (int i = 0; i < 8; ++i) {
        const int r = bm0 + ty * 8 + i;
        if (r >= NROWS) continue;
        float* crow = C + (size_t)r * DIM + bn0 + tx * 8;
        *(float4*)(crow)     = make_float4(acc[i][0], acc[i][1], acc[i][2], acc[i][3]);
        *(float4*)(crow + 4) = make_float4(acc[i][4], acc[i][5], acc[i][6], acc[i][7]);
    }
}

// ---------------- legacy fused gather/scatter GEMM (fallback) ----------------
__global__ __launch_bounds__(256)
void gemm_gs_legacy(const float* __restrict__ A,
                    const float* __restrict__ Wpre, const float* __restrict__ Wsuc,
                    const int* __restrict__ nhp, const int* __restrict__ nhs,
                    const int* __restrict__ pidx, const int* __restrict__ sidx,
                    float* __restrict__ C, int round)
{
    __shared__ float As[BK][LDA];
    __shared__ float Ws[BK][LDB];

    const int tid = threadIdx.x;
    const int tx = tid & 15;
    const int ty = tid >> 4;
    const int bm0 = blockIdx.x * BM;
    const int bn0 = blockIdx.y * BN;

    const int seg = blockIdx.z;
    const int k   = seg >> 1;
    const int dir = seg & 1;
    const float* W  = (dir ? Wsuc : Wpre) + ((size_t)(round * SHOPS + k)) * DIM * DIM;
    const int* g  = (dir ? nhs  : nhp)  + k * NROWS;
    const int* sc = (dir ? pidx : sidx) + k * NROWS;

    float acc[8][8];
    #pragma unroll
    for (int i = 0; i < 8; ++i)
        #pragma unroll
        for (int j = 0; j < 8; ++j) acc[i][j] = 0.0f;

    for (int kt = 0; kt < DIM; kt += BK) {
        #pragma unroll
        for (int it = 0; it < 2; ++it) {
            const int f   = tid + it * 256;
            const int row = f >> 2;
            const int c4  = (f & 3) * 4;
            const int ar = bm0 + row;
            float4 av = make_float4(0.f, 0.f, 0.f, 0.f);
            if (ar < NROWS)
                av = *(const float4*)(A + (size_t)g[ar] * DIM + kt + c4);
            As[c4 + 0][row] = av.x;
            As[c4 + 1][row] = av.y;
            As[c4 + 2][row] = av.z;
            As[c4 + 3][row] = av.w;
            const int wr = bn0 + row;
            const float4 wv = *(const float4*)(W + (size_t)wr * DIM + kt + c4);
            Ws[c4 + 0][row] = wv.x;
            Ws[c4 + 1][row] = wv.y;
            Ws[c4 + 2][row] = wv.z;
            Ws[c4 + 3][row] = wv.w;
        }
        __syncthreads();
        #pragma unroll
        for (int kk = 0; kk < BK; ++kk) {
            const float4 a0 = *(const float4*)&As[kk][ty * 8];
            const float4 a1 = *(const float4*)&As[kk][ty * 8 + 4];
            const float4 b0 = *(const float4*)&Ws[kk][tx * 8];
            const float4 b1 = *(const float4*)&Ws[kk][tx * 8 + 4];
            const float a[8] = {a0.x, a0.y, a0.z, a0.w, a1.x, a1.y, a1.z, a1.w};
            const float b[8] = {b0.x, b0.y, b0.z, b0.w, b1.x, b1.y, b1.z, b1.w};
            #pragma unroll
            for (int i = 0; i < 8; ++i)
                #pragma unroll
                for (int j = 0; j < 8; ++j)
                    acc[i][j] += a[i] * b[j];
        }
        __syncthreads();
    }

    #pragma unroll
    for (int i = 0; i < 8; ++i) {
        const int r = bm0 + ty * 8 + i;
        if (r >= NROWS) continue;
        const int orow = sc[r];
        float* crow = C + (size_t)orow * DIM + bn0 + tx * 8;
        #pragma unroll
        for (int j = 0; j < 8; ++j) atomicAdd(crow + j, acc[i][j]);
    }
}

// ---------------- GroupNorm (1 group) ----------------
template<int MODE>
__global__ __launch_bounds__(256)
void gn_kernel(const float* __restrict__ in, const float* __restrict__ w,
               const float* __restrict__ b, const float* __restrict__ res,
               float* __restrict__ out)
{
    const int lane = threadIdx.x & 63;
    const int wv   = threadIdx.x >> 6;
    const int row  = blockIdx.x * 4 + wv;
    if (row >= NROWS) return;

    const float4 v = *(const float4*)(in + (size_t)row * DIM + lane * 4);
    float s  = v.x + v.y + v.z + v.w;
    float ss = v.x * v.x + v.y * v.y + v.z * v.z + v.w * v.w;
    #pragma unroll
    for (int off = 32; off >= 1; off >>= 1) {
        s  += __shfl_xor(s, off);
        ss += __shfl_xor(ss, off);
    }
    const float m   = s * (1.0f / DIM);
    const float var = ss * (1.0f / DIM) - m * m;
    const float inv = rsqrtf(var + EPSV);

    const float4 wv4 = *(const float4*)(w + lane * 4);
    const float4 bv4 = *(const float4*)(b + lane * 4);
    float4 o;
    o.x = (v.x - m) * inv * wv4.x + bv4.x;
    o.y = (v.y - m) * inv * wv4.y + bv4.y;
    o.z = (v.z - m) * inv * wv4.z + bv4.z;
    o.w = (v.w - m) * inv * wv4.w + bv4.w;

    if (MODE == 0) {
        o.x = fmaxf(o.x, 0.f); o.y = fmaxf(o.y, 0.f);
        o.z = fmaxf(o.z, 0.f); o.w = fmaxf(o.w, 0.f);
    } else {
        const float4 r4 = *(const float4*)(res + (size_t)row * DIM + lane * 4);
        o.x = fmaxf(o.x + r4.x, 0.f); o.y = fmaxf(o.y + r4.y, 0.f);
        o.z = fmaxf(o.z + r4.z, 0.f); o.w = fmaxf(o.w + r4.w, 0.f);
    }
    *(float4*)(out + (size_t)row * DIM + lane * 4) = o;
}

// ---------------- CSR inversion of the 12 scatter maps ----------------
__global__ __launch_bounds__(256)
void count_kernel(const int* __restrict__ pidx, const int* __restrict__ sidx,
                  int* __restrict__ counts)
{
    const int i = blockIdx.x * 256 + threadIdx.x;
    if (i >= NROWS) return;
    const int s = blockIdx.y;           // 0..11
    const int k = s >> 1, dir = s & 1;
    const int* scp = (dir ? pidx : sidx) + k * NROWS;
    atomicAdd(&counts[scp[i]], 1);
}

__global__ __launch_bounds__(256)
void scan_kernel(const int* __restrict__ counts, int* __restrict__ offsets,
                 int* __restrict__ cursor)
{
    __shared__ int wsum[4];
    const int tid = threadIdx.x, lane = tid & 63, wv = tid >> 6;
    int running = 0;
    for (int base = 0; base < NROWS; base += 256) {
        const int i = base + tid;
        const int c = (i < NROWS) ? counts[i] : 0;
        int v = c;
        #pragma unroll
        for (int off = 1; off < 64; off <<= 1) {
            const int t = __shfl_up(v, off);
            if (lane >= off) v += t;
        }
        if (lane == 63) wsum[wv] = v;
        __syncthreads();
        int add = 0;
        for (int w = 0; w < wv; ++w) add += wsum[w];
        const int total = wsum[0] + wsum[1] + wsum[2] + wsum[3];
        const int excl = running + add + v - c;
        if (i < NROWS) { offsets[i] = excl; cursor[i] = excl; }
        running += total;
        __syncthreads();
    }
    if (tid == 0) offsets[NROWS] = running;
}

__global__ __launch_bounds__(256)
void fill_kernel(const int* __restrict__ pidx, const int* __restrict__ sidx,
                 const int* __restrict__ nhp, const int* __restrict__ nhs,
                 int* __restrict__ cursor, int* __restrict__ entries)
{
    const int i = blockIdx.x * 256 + threadIdx.x;
    if (i >= NROWS) return;
    const int s = blockIdx.y;
    const int k = s >> 1, dir = s & 1;
    const int* scp = (dir ? pidx : sidx) + k * NROWS;
    const int* gp  = (dir ? nhs  : nhp)  + k * NROWS;
    const int pos = atomicAdd(&cursor[scp[i]], 1);
    entries[pos] = (s << 16) | gp[i];    // NROWS=50000 < 2^16
}

// temp[r] += sum over CSR entries of row r whose seg is in [c0, c0+nch)
__global__ __launch_bounds__(256)
void combine_kernel(float* __restrict__ TEMP, const float* __restrict__ YBUF,
                    const int* __restrict__ offsets, const int* __restrict__ entries,
                    int c0, int nch)
{
    const int lane = threadIdx.x & 63;
    const int wv   = threadIdx.x >> 6;
    const int r    = blockIdx.x * 4 + wv;
    if (r >= NROWS) return;

    const int e0 = offsets[r], e1 = offsets[r + 1];
    float4 acc = *(const float4*)(TEMP + (size_t)r * DIM + lane * 4);
    bool touched = false;
    for (int e = e0; e < e1; ++e) {
        const int ent = entries[e];
        const int s = ent >> 16;
        if (s >= c0 && s < c0 + nch) {
            const int src = ent & 0xFFFF;
            const float4 yv = *(const float4*)(YBUF + ((size_t)(s - c0) * NROWS + src) * DIM + lane * 4);
            acc.x += yv.x; acc.y += yv.y; acc.z += yv.z; acc.w += yv.w;
            touched = true;
        }
    }
    if (touched)
        *(float4*)(TEMP + (size_t)r * DIM + lane * 4) = acc;
}

extern "C" void kernel_launch(void* const* d_in, const int* in_sizes, int n_in,
                              void* d_out, int out_size, void* d_ws, size_t ws_size,
                              hipStream_t stream)
{
    const float* lane   = (const float*)d_in[0];
    const float* W_ctr  = (const float*)d_in[1];
    const float* norm_w = (const float*)d_in[2];
    const float* norm_b = (const float*)d_in[3];
    const float* W_ctr2 = (const float*)d_in[4];
    const float* c2w    = (const float*)d_in[5];
    const float* c2b    = (const float*)d_in[6];
    const float* W_pre  = (const float*)d_in[7];
    const float* W_suc  = (const float*)d_in[8];
    const int*   pidx   = (const int*)d_in[9];
    const int*   sidx   = (const int*)d_in[10];
    const int*   nhp    = (const int*)d_in[11];
    const int*   nhs    = (const int*)d_in[12];

    float* X = (float*)d_out;

    float* TEMP    = (float*)d_ws;
    int*   counts  = (int*)(TEMP + ND);
    int*   offsets = counts + NROWS;
    int*   cursor  = offsets + NROWS + 1;
    int*   entries = cursor + NROWS;
    size_t head = ND + (size_t)15 * NROWS + 16;
    head = (head + 3) & ~(size_t)3;
    float* YBUF = (float*)d_ws + head;

    const size_t availf = ws_size / 4;
    int CH = 0;
    if (availf > head) CH = (int)((availf - head) / ND);
    if (CH > 12) CH = 12;

    hipMemcpyAsync(X, lane, ND * sizeof(float), hipMemcpyDeviceToDevice, stream);

    const dim3 blk(256);
    const dim3 gg((NROWS + BM - 1) / BM, DIM / BN, 1);
    const int  rowBlocks = (NROWS + 255) / 256;           // 196
    const int  gnBlocks  = (NROWS + 3) / 4;               // 12500

    if (CH >= 1) {
        // Build inverse CSR once (indices constant across rounds)
        hipMemsetAsync(counts, 0, NROWS * sizeof(int), stream);
        count_kernel<<<dim3(rowBlocks, 12), blk, 0, stream>>>(pidx, sidx, counts);
        scan_kernel<<<1, blk, 0, stream>>>(counts, offsets, cursor);
        fill_kernel<<<dim3(rowBlocks, 12), blk, 0, stream>>>(pidx, sidx, nhp, nhs,
                                                             cursor, entries);
        for (int i = 0; i < ROUNDS; ++i) {
            // temp = x @ W_ctr[i].T
            gemm_k<0><<<gg, blk, 0, stream>>>(X, W_ctr + (size_t)i * DIM * DIM,
                                              nullptr, nullptr, TEMP, nullptr, i, 0);
            // message GEMMs + gather-combine, chunked by scratch capacity
            for (int c0 = 0; c0 < 12; c0 += CH) {
                const int nz = (12 - c0 < CH) ? (12 - c0) : CH;
                const dim3 gb((NROWS + BM - 1) / BM, DIM / BN, nz);
                gemm_k<1><<<gb, blk, 0, stream>>>(X, nullptr, W_pre, W_suc,
                                                  nullptr, YBUF, i, c0);
                combine_kernel<<<gnBlocks, blk, 0, stream>>>(TEMP, YBUF, offsets,
                                                             entries, c0, nz);
            }
            gn_kernel<0><<<gnBlocks, blk, 0, stream>>>(TEMP, norm_w + i * DIM,
                                                       norm_b + i * DIM, nullptr, TEMP);
            gemm_k<0><<<gg, blk, 0, stream>>>(TEMP, W_ctr2 + (size_t)i * DIM * DIM,
                                              nullptr, nullptr, YBUF, nullptr, i, 0);
            gn_kernel<1><<<gnBlocks, blk, 0, stream>>>(YBUF, c2w + i * DIM,
                                                       c2b + i * DIM, X, X);
        }
    } else {
        // Fallback: proven round-1 atomic path (needs only 2*ND floats)
        float* Y = TEMP + ND;
        const dim3 gb((NROWS + BM - 1) / BM, DIM / BN, 12);
        for (int i = 0; i < ROUNDS; ++i) {
            gemm_k<0><<<gg, blk, 0, stream>>>(X, W_ctr + (size_t)i * DIM * DIM,
                                              nullptr, nullptr, TEMP, nullptr, i, 0);
            gemm_gs_legacy<<<gb, blk, 0, stream>>>(X, W_pre, W_suc, nhp, nhs,
                                                   pidx, sidx, TEMP, i);
            gn_kernel<0><<<gnBlocks, blk, 0, stream>>>(TEMP, norm_w + i * DIM,
                                                       norm_b + i * DIM, nullptr, TEMP);
            gemm_k<0><<<gg, blk, 0, stream>>>(TEMP, W_ctr2 + (size_t)i * DIM * DIM,
                                              nullptr, nullptr, Y, nullptr, i, 0);
            gn_kernel<1><<<gnBlocks, blk, 0, stream>>>(Y, c2w + i * DIM,
                                                       c2b + i * DIM, X, X);
        }
    }
}

// Round 3
// 1961.206 us; speedup vs baseline: 9.7299x; 4.1736x over previous
//
#include <hip/hip_runtime.h>

#define NROWS 50000
#define DIM   256
#define SHOPS 6
#define ROUNDS 4
#define EPSV  1e-5f
#define ND ((size_t)NROWS * DIM)

typedef _Float16 f16x8 __attribute__((ext_vector_type(8)));
typedef _Float16 f16x4 __attribute__((ext_vector_type(4)));
typedef float    f32x4 __attribute__((ext_vector_type(4)));

// global -> LDS async 16B copy (dest = wave-uniform base + lane*16)
#define GLDS16(GP, LP) \
    __builtin_amdgcn_global_load_lds((const __attribute__((address_space(1))) unsigned*)(GP), \
                                     (__attribute__((address_space(3))) unsigned*)(LP), 16, 0, 0)

// ---------------------------------------------------------------------------
// fp16 MFMA GEMM: C = A @ W^T.  A: [NROWS][256] fp16, W: [256][256] fp16.
// Block 256 thr = 4 waves (2x2), tile 128x128, BK=64, 16x16x32 MFMA.
// Weight matrix = WH + (base_slot + blockIdx.z) * 65536.
// OUTF16=0: write fp32 C32 (z must be 0). OUTF16=1: write fp16 C16 + z*ND.
// LDS tiles XOR-swizzled: physical 16B-slot = logical_slot ^ (row & 7);
// achieved by pre-swizzling the *global source* (linear LDS dest, m173).
// ---------------------------------------------------------------------------
template<int OUTF16>
__global__ __launch_bounds__(256)
void gemm_f16(const _Float16* __restrict__ A, const _Float16* __restrict__ WH,
              int base_slot, float* __restrict__ C32, _Float16* __restrict__ C16)
{
    __shared__ _Float16 lds[16384];           // A tile 16KB @0, W tile 16KB @16384B
    char* ldsb = (char*)lds;

    const int tid = threadIdx.x;
    const int l   = tid & 63;
    const int w   = tid >> 6;
    const int wm  = w & 1;                    // wave row (2)
    const int wn  = w >> 1;                   // wave col (2)
    const int bm0 = blockIdx.x * 128;
    const int bn0 = blockIdx.y * 128;
    const size_t z = blockIdx.z;

    const char* Ab = (const char*)A;
    const char* Wb = (const char*)(WH + (size_t)(base_slot + z) * (DIM * DIM));

    f32x4 acc[4][4];
    #pragma unroll
    for (int mt = 0; mt < 4; ++mt)
        #pragma unroll
        for (int nt = 0; nt < 4; ++nt)
            acc[mt][nt] = (f32x4){0.f, 0.f, 0.f, 0.f};

    for (int kt = 0; kt < 256; kt += 64) {
        // ---- stage A & W tiles (8 global_load_lds per wave) ----
        #pragma unroll
        for (int q = 0; q < 4; ++q) {
            const int f    = (w * 4 + q) * 64 + l;   // 16B chunk id, 0..1023
            const int row  = f >> 3;                 // 0..127
            const int sl   = f & 7;                  // physical 16B slot in row
            const int slog = sl ^ (row & 7);         // logical slot (inverse swizzle)
            const int ar   = min(bm0 + row, NROWS - 1);
            GLDS16(Ab + (size_t)ar * 512 + kt * 2 + slog * 16,
                   ldsb + (w * 4 + q) * 1024);
            GLDS16(Wb + (size_t)(bn0 + row) * 512 + kt * 2 + slog * 16,
                   ldsb + 16384 + (w * 4 + q) * 1024);
        }
        __syncthreads();

        // ---- compute: 2 k-sub-steps of 32, 16 MFMA each ----
        #pragma unroll
        for (int ks = 0; ks < 2; ++ks) {
            f16x8 af[4], bf[4];
            const int slot = (l >> 4) + ks * 4;      // logical 16B slot
            #pragma unroll
            for (int mt = 0; mt < 4; ++mt) {
                const int r = wm * 64 + mt * 16 + (l & 15);
                af[mt] = *(const f16x8*)(ldsb + r * 128 + ((slot ^ (r & 7)) << 4));
            }
            #pragma unroll
            for (int nt = 0; nt < 4; ++nt) {
                const int r = wn * 64 + nt * 16 + (l & 15);
                bf[nt] = *(const f16x8*)(ldsb + 16384 + r * 128 + ((slot ^ (r & 7)) << 4));
            }
            #pragma unroll
            for (int mt = 0; mt < 4; ++mt)
                #pragma unroll
                for (int nt = 0; nt < 4; ++nt)
                    acc[mt][nt] = __builtin_amdgcn_mfma_f32_16x16x32_f16(
                        af[mt], bf[nt], acc[mt][nt], 0, 0, 0);
        }
        __syncthreads();
    }

    // ---- epilogue: D col = lane&15, row = (lane>>4)*4 + j ----
    const int colb = bn0 + wn * 64 + (l & 15);
    #pragma unroll
    for (int mt = 0; mt < 4; ++mt) {
        #pragma unroll
        for (int j = 0; j < 4; ++j) {
            const int row = bm0 + wm * 64 + mt * 16 + (l >> 4) * 4 + j;
            if (row < NROWS) {
                #pragma unroll
                for (int nt = 0; nt < 4; ++nt) {
                    const int col = colb + nt * 16;
                    if (OUTF16)
                        C16[z * ND + (size_t)row * DIM + col] = (_Float16)acc[mt][nt][j];
                    else
                        C32[(size_t)row * DIM + col] = acc[mt][nt][j];
                }
            }
        }
    }
}

// ---------------------------------------------------------------------------
// Weight conversion: pack all 56 matrices fp32 -> fp16 bank.
// Layout: slot r*12+s (s=2k+dir) = msg weights; 48+i = ctr; 52+i = ctr2.
// ---------------------------------------------------------------------------
__global__ __launch_bounds__(256)
void convert_w(const float* __restrict__ Wctr, const float* __restrict__ Wctr2,
               const float* __restrict__ Wpre, const float* __restrict__ Wsuc,
               _Float16* __restrict__ WH)
{
    const size_t i4 = (size_t)blockIdx.x * 256 + threadIdx.x;
    const size_t NT = (size_t)56 * DIM * DIM / 4;
    if (i4 >= NT) return;
    const size_t e = i4 * 4;
    const int slot = (int)(e >> 16);
    const int off  = (int)(e & 65535);
    const float* src;
    if (slot < 48) {
        const int r = slot / 12, s = slot % 12, k = s >> 1, dir = s & 1;
        src = (dir ? Wsuc : Wpre) + (((size_t)r * SHOPS + k) << 16) + off;
    } else if (slot < 52) {
        src = Wctr + ((size_t)(slot - 48) << 16) + off;
    } else {
        src = Wctr2 + ((size_t)(slot - 52) << 16) + off;
    }
    const float4 v = *(const float4*)src;
    f16x4 h;
    h[0] = (_Float16)v.x; h[1] = (_Float16)v.y;
    h[2] = (_Float16)v.z; h[3] = (_Float16)v.w;
    *(f16x4*)(WH + e) = h;
}

// X = lane (fp32) and Xh = fp16 copy
__global__ __launch_bounds__(256)
void init_x(const float* __restrict__ lane, float* __restrict__ X,
            _Float16* __restrict__ Xh)
{
    const size_t i4 = (size_t)blockIdx.x * 256 + threadIdx.x;
    if (i4 >= ND / 4) return;
    const float4 v = *(const float4*)(lane + i4 * 4);
    *(float4*)(X + i4 * 4) = v;
    f16x4 h;
    h[0] = (_Float16)v.x; h[1] = (_Float16)v.y;
    h[2] = (_Float16)v.z; h[3] = (_Float16)v.w;
    *(f16x4*)(Xh + i4 * 4) = h;
}

// ---------------------------------------------------------------------------
// GroupNorm (1 group over 256). One wave per row.
// gn0: in fp32 TEMP -> Hh fp16 = relu(gn(temp)*w+b)
// gn1: in fp16 Y2, res fp32 X -> X fp32 & Xh fp16 = relu(gn(y)*w+b + res)
// ---------------------------------------------------------------------------
__global__ __launch_bounds__(256)
void gn0_kernel(const float* __restrict__ in, const float* __restrict__ w,
                const float* __restrict__ b, _Float16* __restrict__ outh)
{
    const int lane = threadIdx.x & 63;
    const int wv   = threadIdx.x >> 6;
    const int row  = blockIdx.x * 4 + wv;
    if (row >= NROWS) return;

    const float4 v = *(const float4*)(in + (size_t)row * DIM + lane * 4);
    float s  = v.x + v.y + v.z + v.w;
    float ss = v.x * v.x + v.y * v.y + v.z * v.z + v.w * v.w;
    #pragma unroll
    for (int off = 32; off >= 1; off >>= 1) {
        s  += __shfl_xor(s, off);
        ss += __shfl_xor(ss, off);
    }
    const float m   = s * (1.0f / DIM);
    const float var = ss * (1.0f / DIM) - m * m;
    const float inv = rsqrtf(var + EPSV);

    const float4 wv4 = *(const float4*)(w + lane * 4);
    const float4 bv4 = *(const float4*)(b + lane * 4);
    f16x4 o;
    o[0] = (_Float16)fmaxf((v.x - m) * inv * wv4.x + bv4.x, 0.f);
    o[1] = (_Float16)fmaxf((v.y - m) * inv * wv4.y + bv4.y, 0.f);
    o[2] = (_Float16)fmaxf((v.z - m) * inv * wv4.z + bv4.z, 0.f);
    o[3] = (_Float16)fmaxf((v.w - m) * inv * wv4.w + bv4.w, 0.f);
    *(f16x4*)(outh + (size_t)row * DIM + lane * 4) = o;
}

__global__ __launch_bounds__(256)
void gn1_kernel(const _Float16* __restrict__ inh, const float* __restrict__ w,
                const float* __restrict__ b, float* __restrict__ X,
                _Float16* __restrict__ Xh)
{
    const int lane = threadIdx.x & 63;
    const int wv   = threadIdx.x >> 6;
    const int row  = blockIdx.x * 4 + wv;
    if (row >= NROWS) return;

    const f16x4 hv = *(const f16x4*)(inh + (size_t)row * DIM + lane * 4);
    float4 v;
    v.x = (float)hv[0]; v.y = (float)hv[1]; v.z = (float)hv[2]; v.w = (float)hv[3];
    float s  = v.x + v.y + v.z + v.w;
    float ss = v.x * v.x + v.y * v.y + v.z * v.z + v.w * v.w;
    #pragma unroll
    for (int off = 32; off >= 1; off >>= 1) {
        s  += __shfl_xor(s, off);
        ss += __shfl_xor(ss, off);
    }
    const float m   = s * (1.0f / DIM);
    const float var = ss * (1.0f / DIM) - m * m;
    const float inv = rsqrtf(var + EPSV);

    const float4 wv4 = *(const float4*)(w + lane * 4);
    const float4 bv4 = *(const float4*)(b + lane * 4);
    const float4 r4  = *(const float4*)(X + (size_t)row * DIM + lane * 4);
    float4 o;
    o.x = fmaxf((v.x - m) * inv * wv4.x + bv4.x + r4.x, 0.f);
    o.y = fmaxf((v.y - m) * inv * wv4.y + bv4.y + r4.y, 0.f);
    o.z = fmaxf((v.z - m) * inv * wv4.z + bv4.z + r4.z, 0.f);
    o.w = fmaxf((v.w - m) * inv * wv4.w + bv4.w + r4.w, 0.f);
    *(float4*)(X + (size_t)row * DIM + lane * 4) = o;
    f16x4 oh;
    oh[0] = (_Float16)o.x; oh[1] = (_Float16)o.y;
    oh[2] = (_Float16)o.z; oh[3] = (_Float16)o.w;
    *(f16x4*)(Xh + (size_t)row * DIM + lane * 4) = oh;
}

// ---------------------------------------------------------------------------
// CSR inversion of the 12 scatter maps (built once; indices are constant)
// ---------------------------------------------------------------------------
__global__ __launch_bounds__(256)
void count_kernel(const int* __restrict__ pidx, const int* __restrict__ sidx,
                  int* __restrict__ counts)
{
    const int i = blockIdx.x * 256 + threadIdx.x;
    if (i >= NROWS) return;
    const int s = blockIdx.y;
    const int k = s >> 1, dir = s & 1;
    const int* scp = (dir ? pidx : sidx) + k * NROWS;
    atomicAdd(&counts[scp[i]], 1);
}

__global__ __launch_bounds__(256)
void scan_kernel(const int* __restrict__ counts, int* __restrict__ offsets,
                 int* __restrict__ cursor)
{
    __shared__ int wsum[4];
    const int tid = threadIdx.x, lane = tid & 63, wv = tid >> 6;
    int running = 0;
    for (int base = 0; base < NROWS; base += 256) {
        const int i = base + tid;
        const int c = (i < NROWS) ? counts[i] : 0;
        int v = c;
        #pragma unroll
        for (int off = 1; off < 64; off <<= 1) {
            const int t = __shfl_up(v, off);
            if (lane >= off) v += t;
        }
        if (lane == 63) wsum[wv] = v;
        __syncthreads();
        int add = 0;
        for (int ww = 0; ww < wv; ++ww) add += wsum[ww];
        const int total = wsum[0] + wsum[1] + wsum[2] + wsum[3];
        const int excl = running + add + v - c;
        if (i < NROWS) { offsets[i] = excl; cursor[i] = excl; }
        running += total;
        __syncthreads();
    }
    if (tid == 0) offsets[NROWS] = running;
}

__global__ __launch_bounds__(256)
void fill_kernel(const int* __restrict__ pidx, const int* __restrict__ sidx,
                 const int* __restrict__ nhp, const int* __restrict__ nhs,
                 int* __restrict__ cursor, int* __restrict__ entries)
{
    const int i = blockIdx.x * 256 + threadIdx.x;
    if (i >= NROWS) return;
    const int s = blockIdx.y;
    const int k = s >> 1, dir = s & 1;
    const int* scp = (dir ? pidx : sidx) + k * NROWS;
    const int* gp  = (dir ? nhs  : nhp)  + k * NROWS;
    const int pos = atomicAdd(&cursor[scp[i]], 1);
    entries[pos] = (s << 16) | gp[i];
}

// temp[r] += sum of fp16 Y rows for CSR entries of r with seg in [c0, c0+nch)
__global__ __launch_bounds__(256)
void combine_f16(float* __restrict__ TEMP, const _Float16* __restrict__ YB,
                 const int* __restrict__ offsets, const int* __restrict__ entries,
                 int c0, int nch)
{
    const int lane = threadIdx.x & 63;
    const int wv   = threadIdx.x >> 6;
    const int r    = blockIdx.x * 4 + wv;
    if (r >= NROWS) return;

    const int e0 = offsets[r], e1 = offsets[r + 1];
    float4 acc = *(const float4*)(TEMP + (size_t)r * DIM + lane * 4);
    bool touched = false;
    for (int e = e0; e < e1; ++e) {
        const int ent = entries[e];
        const int s = ent >> 16;
        if ((unsigned)(s - c0) < (unsigned)nch) {
            const f16x4 yv = *(const f16x4*)(YB + (size_t)(s - c0) * ND
                                             + (size_t)(ent & 0xFFFF) * DIM + lane * 4);
            acc.x += (float)yv[0]; acc.y += (float)yv[1];
            acc.z += (float)yv[2]; acc.w += (float)yv[3];
            touched = true;
        }
    }
    if (touched)
        *(float4*)(TEMP + (size_t)r * DIM + lane * 4) = acc;
}

// ---------------------------------------------------------------------------
extern "C" void kernel_launch(void* const* d_in, const int* in_sizes, int n_in,
                              void* d_out, int out_size, void* d_ws, size_t ws_size,
                              hipStream_t stream)
{
    const float* lane   = (const float*)d_in[0];
    const float* W_ctr  = (const float*)d_in[1];
    const float* norm_w = (const float*)d_in[2];
    const float* norm_b = (const float*)d_in[3];
    const float* W_ctr2 = (const float*)d_in[4];
    const float* c2w    = (const float*)d_in[5];
    const float* c2b    = (const float*)d_in[6];
    const float* W_pre  = (const float*)d_in[7];
    const float* W_suc  = (const float*)d_in[8];
    const int*   pidx   = (const int*)d_in[9];
    const int*   sidx   = (const int*)d_in[10];
    const int*   nhp    = (const int*)d_in[11];
    const int*   nhs    = (const int*)d_in[12];

    float* X = (float*)d_out;

    // ---- workspace layout ----
    char* p = (char*)d_ws;
    float* TEMP    = (float*)p;  p += ND * 4;
    int*   counts  = (int*)p;    p += (size_t)NROWS * 4;
    int*   offsets = (int*)p;    p += (size_t)(NROWS + 4) * 4;   // +pad keeps 16B align
    int*   cursor  = (int*)p;    p += (size_t)NROWS * 4;
    int*   entries = (int*)p;    p += (size_t)12 * NROWS * 4;
    _Float16* Xh   = (_Float16*)p; p += ND * 2;
    _Float16* Hh   = (_Float16*)p; p += ND * 2;
    _Float16* WH   = (_Float16*)p; p += (size_t)56 * DIM * DIM * 2;
    p = (char*)(((uintptr_t)p + 15) & ~(uintptr_t)15);
    _Float16* YBUF = (_Float16*)p;

    const size_t used = (size_t)(p - (char*)d_ws);
    int nslot = (int)((ws_size - used) / (ND * 2));
    if (nslot < 1) nslot = 1;                 // ws proven >= 259MB; cannot trigger
    int CH = nslot > 12 ? 12 : nslot;
    const int nchunks = (12 + CH - 1) / CH;
    CH = (12 + nchunks - 1) / nchunks;        // balance chunk sizes
    _Float16* Y2 = YBUF;                      // ctr2 output aliases slot 0 (safe: ordered)

    const dim3 blk(256);
    const dim3 gg(391, 2, 1);
    const int  rowBlocks = (NROWS + 255) / 256;   // 196
    const int  gnBlocks  = (NROWS + 3) / 4;       // 12500
    const int  cwBlocks  = (int)(((size_t)56 * DIM * DIM / 4 + 255) / 256);
    const int  ixBlocks  = (int)((ND / 4 + 255) / 256);

    // one-time prep
    convert_w<<<cwBlocks, blk, 0, stream>>>(W_ctr, W_ctr2, W_pre, W_suc, WH);
    init_x<<<ixBlocks, blk, 0, stream>>>(lane, X, Xh);
    hipMemsetAsync(counts, 0, NROWS * sizeof(int), stream);
    count_kernel<<<dim3(rowBlocks, 12), blk, 0, stream>>>(pidx, sidx, counts);
    scan_kernel<<<1, blk, 0, stream>>>(counts, offsets, cursor);
    fill_kernel<<<dim3(rowBlocks, 12), blk, 0, stream>>>(pidx, sidx, nhp, nhs,
                                                         cursor, entries);

    for (int i = 0; i < ROUNDS; ++i) {
        // temp = x @ W_ctr[i].T  (fp32 out, initializes TEMP)
        gemm_f16<0><<<gg, blk, 0, stream>>>(Xh, WH, 48 + i, TEMP, nullptr);
        // 12 message GEMMs (fp16 out) + gather-combine, chunked
        for (int c0 = 0; c0 < 12; c0 += CH) {
            const int nz = (12 - c0 < CH) ? (12 - c0) : CH;
            const dim3 gb(391, 2, nz);
            gemm_f16<1><<<gb, blk, 0, stream>>>(Xh, WH, i * 12 + c0, nullptr, YBUF);
            combine_f16<<<gnBlocks, blk, 0, stream>>>(TEMP, YBUF, offsets, entries,
                                                      c0, nz);
        }
        // h = relu(gn(temp)) -> fp16
        gn0_kernel<<<gnBlocks, blk, 0, stream>>>(TEMP, norm_w + i * DIM,
                                                 norm_b + i * DIM, Hh);
        // y = h @ W_ctr2[i].T -> fp16
        gemm_f16<1><<<gg, blk, 0, stream>>>(Hh, WH, 52 + i, nullptr, Y2);
        // x = relu(gn(y) + x) -> X fp32 + Xh fp16
        gn1_kernel<<<gnBlocks, blk, 0, stream>>>(Y2, c2w + i * DIM,
                                                 c2b + i * DIM, X, Xh);
    }
}

// Round 4
// 1668.306 us; speedup vs baseline: 11.4382x; 1.1756x over previous
//
#include <hip/hip_runtime.h>

#define NROWS 50000
#define DIM   256
#define SHOPS 6
#define ROUNDS 4
#define EPSV  1e-5f
#define ND ((size_t)NROWS * DIM)
#define NB  196                              // ceil(NROWS/256)

typedef _Float16 f16x8 __attribute__((ext_vector_type(8)));
typedef _Float16 f16x4 __attribute__((ext_vector_type(4)));
typedef float    f32x4 __attribute__((ext_vector_type(4)));

#define GLDS16(GP, LP) \
    __builtin_amdgcn_global_load_lds((const __attribute__((address_space(1))) unsigned*)(GP), \
                                     (__attribute__((address_space(3))) unsigned*)(LP), 16, 0, 0)

// ---------------------------------------------------------------------------
// fp16 MFMA GEMM: C = A @ W^T. 128x128 tile, 4 waves, BK=64, 16x16x32 MFMA.
// W = WH + (base_slot + z)*65536.  Output fp16 at C16 + z*ND.
// LDS XOR-swizzle via pre-swizzled global source (linear LDS dest).
// ---------------------------------------------------------------------------
__global__ __launch_bounds__(256)
void gemm_f16(const _Float16* __restrict__ A, const _Float16* __restrict__ WH,
              int base_slot, _Float16* __restrict__ C16)
{
    __shared__ _Float16 lds[16384];
    char* ldsb = (char*)lds;

    const int tid = threadIdx.x;
    const int l   = tid & 63;
    const int w   = tid >> 6;
    const int wm  = w & 1;
    const int wn  = w >> 1;
    const int bm0 = blockIdx.x * 128;
    const int bn0 = blockIdx.y * 128;
    const size_t z = blockIdx.z;

    const char* Ab = (const char*)A;
    const char* Wb = (const char*)(WH + (size_t)(base_slot + z) * (DIM * DIM));

    f32x4 acc[4][4];
    #pragma unroll
    for (int mt = 0; mt < 4; ++mt)
        #pragma unroll
        for (int nt = 0; nt < 4; ++nt)
            acc[mt][nt] = (f32x4){0.f, 0.f, 0.f, 0.f};

    for (int kt = 0; kt < 256; kt += 64) {
        #pragma unroll
        for (int q = 0; q < 4; ++q) {
            const int f    = (w * 4 + q) * 64 + l;
            const int row  = f >> 3;
            const int sl   = f & 7;
            const int slog = sl ^ (row & 7);
            const int ar   = min(bm0 + row, NROWS - 1);
            GLDS16(Ab + (size_t)ar * 512 + kt * 2 + slog * 16,
                   ldsb + (w * 4 + q) * 1024);
            GLDS16(Wb + (size_t)(bn0 + row) * 512 + kt * 2 + slog * 16,
                   ldsb + 16384 + (w * 4 + q) * 1024);
        }
        __syncthreads();

        #pragma unroll
        for (int ks = 0; ks < 2; ++ks) {
            f16x8 af[4], bf[4];
            const int slot = (l >> 4) + ks * 4;
            #pragma unroll
            for (int mt = 0; mt < 4; ++mt) {
                const int r = wm * 64 + mt * 16 + (l & 15);
                af[mt] = *(const f16x8*)(ldsb + r * 128 + ((slot ^ (r & 7)) << 4));
            }
            #pragma unroll
            for (int nt = 0; nt < 4; ++nt) {
                const int r = wn * 64 + nt * 16 + (l & 15);
                bf[nt] = *(const f16x8*)(ldsb + 16384 + r * 128 + ((slot ^ (r & 7)) << 4));
            }
            #pragma unroll
            for (int mt = 0; mt < 4; ++mt)
                #pragma unroll
                for (int nt = 0; nt < 4; ++nt)
                    acc[mt][nt] = __builtin_amdgcn_mfma_f32_16x16x32_f16(
                        af[mt], bf[nt], acc[mt][nt], 0, 0, 0);
        }
        __syncthreads();
    }

    const int colb = bn0 + wn * 64 + (l & 15);
    #pragma unroll
    for (int mt = 0; mt < 4; ++mt) {
        #pragma unroll
        for (int j = 0; j < 4; ++j) {
            const int row = bm0 + wm * 64 + mt * 16 + (l >> 4) * 4 + j;
            if (row < NROWS) {
                #pragma unroll
                for (int nt = 0; nt < 4; ++nt)
                    C16[z * ND + (size_t)row * DIM + colb + nt * 16] =
                        (_Float16)acc[mt][nt][j];
            }
        }
    }
}

// ---------------------------------------------------------------------------
__global__ __launch_bounds__(256)
void convert_w(const float* __restrict__ Wctr, const float* __restrict__ Wctr2,
               const float* __restrict__ Wpre, const float* __restrict__ Wsuc,
               _Float16* __restrict__ WH)
{
    const size_t i4 = (size_t)blockIdx.x * 256 + threadIdx.x;
    const size_t NT = (size_t)56 * DIM * DIM / 4;
    if (i4 >= NT) return;
    const size_t e = i4 * 4;
    const int slot = (int)(e >> 16);
    const int off  = (int)(e & 65535);
    const float* src;
    if (slot < 48) {
        const int r = slot / 12, s = slot % 12, k = s >> 1, dir = s & 1;
        src = (dir ? Wsuc : Wpre) + (((size_t)r * SHOPS + k) << 16) + off;
    } else if (slot < 52) {
        src = Wctr + ((size_t)(slot - 48) << 16) + off;
    } else {
        src = Wctr2 + ((size_t)(slot - 52) << 16) + off;
    }
    const float4 v = *(const float4*)src;
    f16x4 h;
    h[0] = (_Float16)v.x; h[1] = (_Float16)v.y;
    h[2] = (_Float16)v.z; h[3] = (_Float16)v.w;
    *(f16x4*)(WH + e) = h;
}

__global__ __launch_bounds__(256)
void init_x(const float* __restrict__ lane, float* __restrict__ X,
            _Float16* __restrict__ Xh)
{
    const size_t i4 = (size_t)blockIdx.x * 256 + threadIdx.x;
    if (i4 >= ND / 4) return;
    const float4 v = *(const float4*)(lane + i4 * 4);
    *(float4*)(X + i4 * 4) = v;
    f16x4 h;
    h[0] = (_Float16)v.x; h[1] = (_Float16)v.y;
    h[2] = (_Float16)v.z; h[3] = (_Float16)v.w;
    *(f16x4*)(Xh + i4 * 4) = h;
}

// x = relu(gn(y)*w+b + res) -> X fp32 + Xh fp16
__global__ __launch_bounds__(256)
void gn1_kernel(const _Float16* __restrict__ inh, const float* __restrict__ w,
                const float* __restrict__ b, float* __restrict__ X,
                _Float16* __restrict__ Xh)
{
    const int lane = threadIdx.x & 63;
    const int wv   = threadIdx.x >> 6;
    const int row  = blockIdx.x * 4 + wv;
    if (row >= NROWS) return;

    const f16x4 hv = *(const f16x4*)(inh + (size_t)row * DIM + lane * 4);
    float4 v;
    v.x = (float)hv[0]; v.y = (float)hv[1]; v.z = (float)hv[2]; v.w = (float)hv[3];
    float s  = v.x + v.y + v.z + v.w;
    float ss = v.x * v.x + v.y * v.y + v.z * v.z + v.w * v.w;
    #pragma unroll
    for (int off = 32; off >= 1; off >>= 1) {
        s  += __shfl_xor(s, off);
        ss += __shfl_xor(ss, off);
    }
    const float m   = s * (1.0f / DIM);
    const float var = ss * (1.0f / DIM) - m * m;
    const float inv = rsqrtf(var + EPSV);

    const float4 wv4 = *(const float4*)(w + lane * 4);
    const float4 bv4 = *(const float4*)(b + lane * 4);
    const float4 r4  = *(const float4*)(X + (size_t)row * DIM + lane * 4);
    float4 o;
    o.x = fmaxf((v.x - m) * inv * wv4.x + bv4.x + r4.x, 0.f);
    o.y = fmaxf((v.y - m) * inv * wv4.y + bv4.y + r4.y, 0.f);
    o.z = fmaxf((v.z - m) * inv * wv4.z + bv4.z + r4.z, 0.f);
    o.w = fmaxf((v.w - m) * inv * wv4.w + bv4.w + r4.w, 0.f);
    *(float4*)(X + (size_t)row * DIM + lane * 4) = o;
    f16x4 oh;
    oh[0] = (_Float16)o.x; oh[1] = (_Float16)o.y;
    oh[2] = (_Float16)o.z; oh[3] = (_Float16)o.w;
    *(f16x4*)(Xh + (size_t)row * DIM + lane * 4) = oh;
}

// ---------------------------------------------------------------------------
// CSR inversion (once per launch; indices constant across rounds)
// ---------------------------------------------------------------------------
__global__ __launch_bounds__(256)
void count_kernel(const int* __restrict__ pidx, const int* __restrict__ sidx,
                  int* __restrict__ counts)
{
    const int i = blockIdx.x * 256 + threadIdx.x;
    if (i >= NROWS) return;
    const int s = blockIdx.y;
    const int k = s >> 1, dir = s & 1;
    const int* scp = (dir ? pidx : sidx) + k * NROWS;
    atomicAdd(&counts[scp[i]], 1);
}

// pass 1: per-block exclusive scan + block totals
__global__ __launch_bounds__(256)
void scan1_kernel(const int* __restrict__ counts, int* __restrict__ offs,
                  int* __restrict__ bsum)
{
    __shared__ int wsum[4];
    const int tid = threadIdx.x, lane = tid & 63, wv = tid >> 6;
    const int i = blockIdx.x * 256 + tid;
    const int c = (i < NROWS) ? counts[i] : 0;
    int v = c;
    #pragma unroll
    for (int off = 1; off < 64; off <<= 1) {
        const int t = __shfl_up(v, off);
        if (lane >= off) v += t;
    }
    if (lane == 63) wsum[wv] = v;
    __syncthreads();
    int add = 0;
    for (int w = 0; w < wv; ++w) add += wsum[w];
    if (i < NROWS) offs[i] = add + v - c;
    if (tid == 255) bsum[blockIdx.x] = wsum[0] + wsum[1] + wsum[2] + wsum[3];
}

// pass 2: single block scans the 196 block totals -> exclusive prefixes
__global__ __launch_bounds__(256)
void scan2_kernel(const int* __restrict__ bsum, int* __restrict__ bpre)
{
    __shared__ int wsum[4];
    const int tid = threadIdx.x, lane = tid & 63, wv = tid >> 6;
    const int c = (tid < NB) ? bsum[tid] : 0;
    int v = c;
    #pragma unroll
    for (int off = 1; off < 64; off <<= 1) {
        const int t = __shfl_up(v, off);
        if (lane >= off) v += t;
    }
    if (lane == 63) wsum[wv] = v;
    __syncthreads();
    int add = 0;
    for (int w = 0; w < wv; ++w) add += wsum[w];
    if (tid < NB) bpre[tid] = add + v - c;
}

// pass 3: add block prefix; init cursor; set sentinel
__global__ __launch_bounds__(256)
void scan3_kernel(int* __restrict__ offs, const int* __restrict__ bpre,
                  int* __restrict__ cursor)
{
    const int i = blockIdx.x * 256 + threadIdx.x;
    if (i < NROWS) {
        const int v = offs[i] + bpre[blockIdx.x];
        offs[i] = v;
        cursor[i] = v;
    }
    if (i == 0) offs[NROWS] = 12 * NROWS;
}

__global__ __launch_bounds__(256)
void fill_kernel(const int* __restrict__ pidx, const int* __restrict__ sidx,
                 const int* __restrict__ nhp, const int* __restrict__ nhs,
                 int* __restrict__ cursor, int* __restrict__ entries)
{
    const int i = blockIdx.x * 256 + threadIdx.x;
    if (i >= NROWS) return;
    const int s = blockIdx.y;
    const int k = s >> 1, dir = s & 1;
    const int* scp = (dir ? pidx : sidx) + k * NROWS;
    const int* gp  = (dir ? nhs  : nhp)  + k * NROWS;
    const int pos = atomicAdd(&cursor[scp[i]], 1);
    entries[pos] = (s << 16) | gp[i];
}

// ---------------------------------------------------------------------------
// combine: acc = (FIRST ? YC[r] : TEMP16[r]) + sum of Y rows for entries with
// seg in [c0, c0+nch). LAST: fused GroupNorm+ReLU -> Hh. else -> TEMP16.
// ---------------------------------------------------------------------------
template<int FIRST, int LAST>
__global__ __launch_bounds__(256)
void combine_f16(const _Float16* __restrict__ YC, _Float16* __restrict__ TEMP16,
                 const _Float16* __restrict__ YB,
                 const int* __restrict__ offsets, const int* __restrict__ entries,
                 int c0, int nch,
                 const float* __restrict__ gw, const float* __restrict__ gb,
                 _Float16* __restrict__ Hh)
{
    const int lane = threadIdx.x & 63;
    const int wv   = threadIdx.x >> 6;
    const int r    = blockIdx.x * 4 + wv;
    if (r >= NROWS) return;
    const size_t rowoff = (size_t)r * DIM + lane * 4;

    const f16x4 iv = FIRST ? *(const f16x4*)(YC + rowoff)
                           : *(const f16x4*)(TEMP16 + rowoff);
    float4 acc;
    acc.x = (float)iv[0]; acc.y = (float)iv[1];
    acc.z = (float)iv[2]; acc.w = (float)iv[3];

    const int e0 = offsets[r], e1 = offsets[r + 1];
    for (int e = e0; e < e1; ++e) {
        const int ent = entries[e];
        const int s = ent >> 16;
        if ((unsigned)(s - c0) < (unsigned)nch) {
            const f16x4 yv = *(const f16x4*)(YB + (size_t)(s - c0) * ND
                                             + (size_t)(ent & 0xFFFF) * DIM + lane * 4);
            acc.x += (float)yv[0]; acc.y += (float)yv[1];
            acc.z += (float)yv[2]; acc.w += (float)yv[3];
        }
    }

    if (LAST) {
        float s  = acc.x + acc.y + acc.z + acc.w;
        float ss = acc.x * acc.x + acc.y * acc.y + acc.z * acc.z + acc.w * acc.w;
        #pragma unroll
        for (int off = 32; off >= 1; off >>= 1) {
            s  += __shfl_xor(s, off);
            ss += __shfl_xor(ss, off);
        }
        const float m   = s * (1.0f / DIM);
        const float var = ss * (1.0f / DIM) - m * m;
        const float inv = rsqrtf(var + EPSV);
        const float4 wv4 = *(const float4*)(gw + lane * 4);
        const float4 bv4 = *(const float4*)(gb + lane * 4);
        f16x4 o;
        o[0] = (_Float16)fmaxf((acc.x - m) * inv * wv4.x + bv4.x, 0.f);
        o[1] = (_Float16)fmaxf((acc.y - m) * inv * wv4.y + bv4.y, 0.f);
        o[2] = (_Float16)fmaxf((acc.z - m) * inv * wv4.z + bv4.z, 0.f);
        o[3] = (_Float16)fmaxf((acc.w - m) * inv * wv4.w + bv4.w, 0.f);
        *(f16x4*)(Hh + rowoff) = o;
    } else {
        f16x4 o;
        o[0] = (_Float16)acc.x; o[1] = (_Float16)acc.y;
        o[2] = (_Float16)acc.z; o[3] = (_Float16)acc.w;
        *(f16x4*)(TEMP16 + rowoff) = o;
    }
}

// ---------------------------------------------------------------------------
extern "C" void kernel_launch(void* const* d_in, const int* in_sizes, int n_in,
                              void* d_out, int out_size, void* d_ws, size_t ws_size,
                              hipStream_t stream)
{
    const float* lane   = (const float*)d_in[0];
    const float* W_ctr  = (const float*)d_in[1];
    const float* norm_w = (const float*)d_in[2];
    const float* norm_b = (const float*)d_in[3];
    const float* W_ctr2 = (const float*)d_in[4];
    const float* c2w    = (const float*)d_in[5];
    const float* c2b    = (const float*)d_in[6];
    const float* W_pre  = (const float*)d_in[7];
    const float* W_suc  = (const float*)d_in[8];
    const int*   pidx   = (const int*)d_in[9];
    const int*   sidx   = (const int*)d_in[10];
    const int*   nhp    = (const int*)d_in[11];
    const int*   nhs    = (const int*)d_in[12];

    float* X = (float*)d_out;

    // ---- workspace layout ----
    char* p = (char*)d_ws;
    int* counts  = (int*)p; p += (size_t)NROWS * 4;
    int* offsets = (int*)p; p += (size_t)(NROWS + 4) * 4;
    int* cursor  = (int*)p; p += (size_t)NROWS * 4;
    int* bsum    = (int*)p; p += 256 * 4;
    int* bpre    = (int*)p; p += 256 * 4;
    int* entries = (int*)p; p += (size_t)12 * NROWS * 4;
    p = (char*)(((uintptr_t)p + 15) & ~(uintptr_t)15);
    _Float16* Xh   = (_Float16*)p; p += ND * 2;
    _Float16* Hh   = (_Float16*)p; p += ND * 2;
    _Float16* T16  = (_Float16*)p; p += ND * 2;
    _Float16* YC   = (_Float16*)p; p += ND * 2;
    _Float16* WH   = (_Float16*)p; p += (size_t)56 * DIM * DIM * 2;
    p = (char*)(((uintptr_t)p + 15) & ~(uintptr_t)15);
    _Float16* YBUF = (_Float16*)p;

    const size_t used = (size_t)(p - (char*)d_ws);
    int nslot = (int)((ws_size - used) / (ND * 2));
    if (nslot < 1) nslot = 1;
    int CH = nslot > 12 ? 12 : nslot;
    const int nchunks = (12 + CH - 1) / CH;
    CH = (12 + nchunks - 1) / nchunks;
    _Float16* Y2 = YBUF;   // ctr2 output reuses slot 0 (stream-ordered, safe)

    const dim3 blk(256);
    const dim3 gg(391, 2, 1);
    const int  gnBlocks = (NROWS + 3) / 4;
    const int  cwBlocks = (int)(((size_t)56 * DIM * DIM / 4 + 255) / 256);
    const int  ixBlocks = (int)((ND / 4 + 255) / 256);

    // one-time prep
    convert_w<<<cwBlocks, blk, 0, stream>>>(W_ctr, W_ctr2, W_pre, W_suc, WH);
    init_x<<<ixBlocks, blk, 0, stream>>>(lane, X, Xh);
    hipMemsetAsync(counts, 0, NROWS * sizeof(int), stream);
    count_kernel<<<dim3(NB, 12), blk, 0, stream>>>(pidx, sidx, counts);
    scan1_kernel<<<NB, blk, 0, stream>>>(counts, offsets, bsum);
    scan2_kernel<<<1, blk, 0, stream>>>(bsum, bpre);
    scan3_kernel<<<NB, blk, 0, stream>>>(offsets, bpre, cursor);
    fill_kernel<<<dim3(NB, 12), blk, 0, stream>>>(pidx, sidx, nhp, nhs,
                                                  cursor, entries);

    for (int i = 0; i < ROUNDS; ++i) {
        // YC = x @ W_ctr[i].T  (fp16)
        gemm_f16<<<gg, blk, 0, stream>>>(Xh, WH, 48 + i, YC);
        // 12 message GEMMs + combine (last chunk fuses GN+ReLU -> Hh)
        for (int c0 = 0; c0 < 12; c0 += CH) {
            const int nz = (12 - c0 < CH) ? (12 - c0) : CH;
            const dim3 gb(391, 2, nz);
            gemm_f16<<<gb, blk, 0, stream>>>(Xh, WH, i * 12 + c0, YBUF);
            const bool first = (c0 == 0);
            const bool last  = (c0 + nz >= 12);
            if (first && last)
                combine_f16<1, 1><<<gnBlocks, blk, 0, stream>>>(YC, T16, YBUF,
                    offsets, entries, c0, nz, norm_w + i * DIM, norm_b + i * DIM, Hh);
            else if (first)
                combine_f16<1, 0><<<gnBlocks, blk, 0, stream>>>(YC, T16, YBUF,
                    offsets, entries, c0, nz, norm_w + i * DIM, norm_b + i * DIM, Hh);
            else if (last)
                combine_f16<0, 1><<<gnBlocks, blk, 0, stream>>>(YC, T16, YBUF,
                    offsets, entries, c0, nz, norm_w + i * DIM, norm_b + i * DIM, Hh);
            else
                combine_f16<0, 0><<<gnBlocks, blk, 0, stream>>>(YC, T16, YBUF,
                    offsets, entries, c0, nz, norm_w + i * DIM, norm_b + i * DIM, Hh);
        }
        // y = h @ W_ctr2[i].T -> fp16
        gemm_f16<<<gg, blk, 0, stream>>>(Hh, WH, 52 + i, Y2);
        // x = relu(gn(y) + x) -> X fp32 + Xh fp16
        gn1_kernel<<<gnBlocks, blk, 0, stream>>>(Y2, c2w + i * DIM,
                                                 c2b + i * DIM, X, Xh);
    }
}